// Round 1
// baseline (473.663 us; speedup 1.0000x reference)
//
#include <hip/hip_runtime.h>
#include <cstdint>

#define B_DIM 32
#define T_DIM 1024
#define NIN 128
#define NHID 1024
#define KSLOT 8
#define NWORDS 34   // 2 guard words (64 zero bits) + 32 data words

// ---------------- prep: pack spike input into per-(b,i) bit columns ----------------
// xbits[b][i][w]: bit (t&31) of word (2 + t/32) = (x[b][t][i] != 0)
__global__ void pack_bits_kernel(const float* __restrict__ x, uint32_t* __restrict__ xbits) {
    int b  = blockIdx.x >> 3;   // 32
    int wg = blockIdx.x & 7;    // 8 groups of 4 words
    int i  = threadIdx.x;       // 128
    const float* xp = x + (size_t)b * T_DIM * NIN + i;
    uint32_t* colp = xbits + ((size_t)b * NIN + i) * NWORDS;
    if (wg == 0) { colp[0] = 0u; colp[1] = 0u; }
    for (int w = wg * 4; w < wg * 4 + 4; ++w) {
        uint32_t word = 0;
        #pragma unroll 4
        for (int bit = 0; bit < 32; ++bit) {
            float xv = xp[(size_t)(w * 32 + bit) * NIN];   // lanes = consecutive i -> coalesced
            word |= (xv != 0.0f) ? (1u << bit) : 0u;
        }
        colp[2 + w] = word;
    }
}

// ---------------- prep: pack (W, delay) into one u32, transposed to [i][h] ----------------
// d = round(sigmoid(draw)*50) in low 6 bits; W f32 with low 6 mantissa bits zeroed in the rest.
__global__ void pack_wd_kernel(const float* __restrict__ W, const float* __restrict__ draw,
                               uint32_t* __restrict__ WdT) {
    int idx = blockIdx.x * blockDim.x + threadIdx.x;   // 131072 = h*128 + i
    int h = idx >> 7, i = idx & 127;
    float w  = W[idx];
    float dr = draw[idx];
    float sg = 1.0f / (1.0f + expf(-dr));
    int d = (int)rintf(sg * 50.0f);                    // RNE matches jnp.round
    uint32_t wd = (__float_as_uint(w) & 0xffffffc0u) | (uint32_t)d;
    WdT[(size_t)i * NHID + h] = wd;
}

// ---------------- prep: zero state / totals, logits = b_ro ----------------
__global__ void init_kernel(float* v_st, float* ref_st, int* totals, float* out,
                            const float* __restrict__ b_ro) {
    int idx = blockIdx.x * blockDim.x + threadIdx.x;
    if (idx < B_DIM * NHID) { v_st[idx] = 0.0f; ref_st[idx] = 0.0f; }
    if (idx < T_DIM) totals[idx] = 0;
    if (idx < B_DIM * KSLOT) out[idx] = b_ro[0];
}

// ---------------- heavy kernel: I[b][t][h] = sum_i W[h,i] * x[b, t-1-d[h,i], i] ----------------
// block = (b, 64-h group), 256 threads = 64 h-lanes x 4 t-chunk subsets; grid = 32*16 = 512
__global__ __launch_bounds__(256, 2) void current_kernel(
    const uint32_t* __restrict__ WdT, const uint32_t* __restrict__ xbits,
    float* __restrict__ I, int slab_t0, int ntc, int slab_len) {
    __shared__ uint32_t lds_wd[NIN * 64];      // [i][hl] 32 KB
    __shared__ uint32_t lds_x[NIN * NWORDS];   // [i][w]  17 KB
    int bx = blockIdx.x;
    int hg = bx & 15;
    int b  = bx >> 4;
    int tid = threadIdx.x;
    int hl  = tid & 63;
    int sub = tid >> 6;
    int hbase = hg * 64;
    for (int idx = tid; idx < NIN * 64; idx += 256)
        lds_wd[idx] = WdT[(size_t)(idx >> 6) * NHID + hbase + (idx & 63)];
    for (int idx = tid; idx < NIN * NWORDS; idx += 256)
        lds_x[idx] = xbits[(size_t)b * NIN * NWORDS + idx];
    __syncthreads();
    int h = hbase + hl;
    for (int tc = sub; tc < ntc; tc += 4) {
        int t0 = slab_t0 + tc * 32;           // global time of acc[0]
        float acc[32];
        #pragma unroll
        for (int k = 0; k < 32; ++k) acc[k] = 0.0f;
        #pragma unroll 2
        for (int i = 0; i < NIN; ++i) {
            uint32_t wd = lds_wd[(i << 6) | hl];      // fixed i per wave -> conflict-free
            int d      = (int)(wd & 63u);
            int wbits  = (int)(wd & 0xffffffc0u);     // W with 6 low mantissa bits dropped
            int sp = t0 + 63 - d;                     // (t0 - 1 - d) + 64 guard bits, >= 13
            int q = sp >> 5, r = sp & 31;
            uint32_t lo = lds_x[i * NWORDS + q];      // <=2 distinct addrs per wave
            uint32_t hi = lds_x[i * NWORDS + q + 1];
            uint32_t mask = (uint32_t)(((((uint64_t)hi) << 32) | lo) >> r);
            // bit k of mask == x[b, t0+k-1-d, i]
            #pragma unroll
            for (int k = 0; k < 32; ++k) {
                int sel = ((int)(mask << (31 - k))) >> 31;   // v_bfe_i32 pattern: 0 or -1
                acc[k] += __int_as_float(wbits & sel);
            }
        }
        float* Ip = I + ((size_t)b * slab_len + tc * 32) * NHID + h;
        #pragma unroll
        for (int k = 0; k < 32; ++k) Ip[(size_t)k * NHID] = acc[k];   // coalesced over h
    }
}

// ---------------- LIF scan: sequential over t, one thread per (b,h) ----------------
__global__ __launch_bounds__(64) void lif_kernel(
    const float* __restrict__ I, float* __restrict__ v_st, float* __restrict__ ref_st,
    int* __restrict__ totals, float* __restrict__ logits,
    const float* __restrict__ w_ro, const int* __restrict__ ss, const int* __restrict__ se,
    int slab_t0, int slab_len) {
    int bx = blockIdx.x;
    int hg = bx & 15;
    int b  = bx >> 4;
    int lane = threadIdx.x;
    int h = hg * 64 + lane;
    int sidx = b * NHID + h;
    float v  = v_st[sidx];
    float rf = ref_st[sidx];
    float sacc[KSLOT];
    int st[KSLOT], en[KSLOT];
    #pragma unroll
    for (int k = 0; k < KSLOT; ++k) { sacc[k] = 0.0f; st[k] = ss[k]; en[k] = se[k]; }
    const float* Ip = I + (size_t)b * slab_len * NHID + h;
    for (int tl = 0; tl < slab_len; tl += 8) {
        float Iv[8];
        #pragma unroll
        for (int u = 0; u < 8; ++u) Iv[u] = Ip[(size_t)(tl + u) * NHID];  // coalesced over h
        #pragma unroll
        for (int u = 0; u < 8; ++u) {
            int t = slab_t0 + tl + u;
            bool active = (rf <= 0.0f);
            float vupd = v + 0.1f * (Iv[u] - v);      // v + alpha*(-v + I)
            float vn = active ? vupd : v;
            bool spike = active && (vn >= 1.0f);
            unsigned long long bal = __ballot(spike);
            if (bal != 0ULL) {                         // rare path (spikes ~never fire)
                if (spike) {
                    vn = 0.0f;                         // V_RESET
                    #pragma unroll
                    for (int k = 0; k < KSLOT; ++k)
                        if (t >= st[k] && t < en[k]) sacc[k] += 1.0f;
                }
                rf = spike ? 2.0f : fmaxf(rf - 1.0f, 0.0f);
                if (lane == 0) atomicAdd(&totals[t], (int)__popcll(bal));
            } else {
                rf = fmaxf(rf - 1.0f, 0.0f);
            }
            v = vn;
        }
    }
    v_st[sidx] = v;
    ref_st[sidx] = rf;
    // logits[b][k] += sum_h sacc[k] * w_ro[h]
    float wr = w_ro[h];
    #pragma unroll
    for (int k = 0; k < KSLOT; ++k) {
        float val = sacc[k] * wr;
        #pragma unroll
        for (int o = 32; o > 0; o >>= 1) val += __shfl_down(val, o);
        if (lane == 0) atomicAdd(&logits[b * KSLOT + k], val);
    }
}

// ---------------- finalize: totals int -> float output ----------------
__global__ void finalize_kernel(const int* __restrict__ totals, float* __restrict__ out) {
    int t = blockIdx.x * blockDim.x + threadIdx.x;
    if (t < T_DIM) out[B_DIM * KSLOT + t] = (float)totals[t];
}

extern "C" void kernel_launch(void* const* d_in, const int* in_sizes, int n_in,
                              void* d_out, int out_size, void* d_ws, size_t ws_size,
                              hipStream_t stream) {
    const float* x   = (const float*)d_in[0];
    const float* W   = (const float*)d_in[1];
    const float* drw = (const float*)d_in[2];
    const float* wro = (const float*)d_in[3];
    const float* bro = (const float*)d_in[4];
    const int*   ss  = (const int*)d_in[5];
    const int*   se  = (const int*)d_in[6];
    float* out = (float*)d_out;

    uintptr_t base = (uintptr_t)d_ws;
    size_t off = 0;
    auto take = [&](size_t bytes) {
        size_t o = off;
        off = (off + bytes + 255) & ~(size_t)255;
        return (void*)(base + o);
    };
    uint32_t* xbits = (uint32_t*)take((size_t)B_DIM * NIN * NWORDS * 4);
    uint32_t* WdT   = (uint32_t*)take((size_t)NIN * NHID * 4);
    float* v_st     = (float*)take((size_t)B_DIM * NHID * 4);
    float* ref_st   = (float*)take((size_t)B_DIM * NHID * 4);
    int* totals     = (int*)take((size_t)T_DIM * 4);
    size_t fixed = off;
    int slab = 1024;                 // t-slab for the I intermediate; shrink if ws is small
    while (slab > 32 && fixed + (size_t)B_DIM * slab * NHID * 4 > ws_size) slab >>= 1;
    float* Ibuf = (float*)take((size_t)B_DIM * slab * NHID * 4);

    pack_bits_kernel<<<256, 128, 0, stream>>>(x, xbits);
    pack_wd_kernel<<<512, 256, 0, stream>>>(W, drw, WdT);
    init_kernel<<<128, 256, 0, stream>>>(v_st, ref_st, totals, out, bro);
    for (int s0 = 0; s0 < T_DIM; s0 += slab) {
        current_kernel<<<512, 256, 0, stream>>>(WdT, xbits, Ibuf, s0, slab / 32, slab);
        lif_kernel<<<512, 64, 0, stream>>>(Ibuf, v_st, ref_st, totals, out, wro, ss, se, s0, slab);
    }
    finalize_kernel<<<4, 256, 0, stream>>>(totals, out);
}